// Round 1
// baseline (853.492 us; speedup 1.0000x reference)
//
#include <hip/hip_runtime.h>

#define BLOCK 256
#define GRID_CAP 8192LL

// Lane L of every wave holds code = sorted_vals[L] (64 lanes == 64 codebook
// entries). Branchless capped binary search via ds_bpermute (__shfl):
// pos = min(#vals < x, 63); idx = clip(pos, 1, 63); pick nearer of
// sorted[idx-1], sorted[idx] with ties to the lower — bit-exact vs reference.
__device__ __forceinline__ float nearest_code(float x, float code) {
    int pos = 0;
#pragma unroll
    for (int k = 32; k >= 1; k >>= 1) {
        float v = __shfl(code, pos + k - 1);
        if (v < x) pos += k;
    }
    int idx = pos < 1 ? 1 : pos;       // clip(pos,1,63); pos already <= 63
    float lo = __shfl(code, idx - 1);
    float hi = __shfl(code, idx);
    return (fabsf(x - lo) <= fabsf(x - hi)) ? lo : hi;
}

__global__ __launch_bounds__(BLOCK) void fp6_nearest_kernel(
    const float* __restrict__ x, const float* __restrict__ vals,
    float* __restrict__ out, long long n) {
    __shared__ float s_sorted[64];
    const int tid = threadIdx.x;

    // Rank-sort the 64 codebook values (input is already sorted, but the
    // reference sorts — this is cheap insurance, once per block).
    if (tid < 64) {
        float v = vals[tid];
        int rank = 0;
#pragma unroll 8
        for (int j = 0; j < 64; ++j) {
            float w = vals[j];
            rank += (w < v) || (w == v && j < tid);
        }
        s_sorted[rank] = v;
    }
    __syncthreads();
    const float code = s_sorted[tid & 63];  // broadcast-free register copy

    const long long n4 = n >> 2;
    const float4* __restrict__ x4 = (const float4*)x;
    float4* __restrict__ o4 = (float4*)out;
    const long long stride = (long long)gridDim.x * BLOCK;
    const int lane = tid & 63;
    const long long wave_off = (long long)blockIdx.x * BLOCK + (tid & ~63);

    // Main vectorized loop. Loop condition is wave-uniform (b excludes lane)
    // so every lane is active at the shuffles; loads/stores are guarded.
    for (long long b = wave_off; b < n4; b += stride) {
        const long long i = b + lane;
        const bool ok = i < n4;
        float4 v = ok ? x4[i] : make_float4(0.f, 0.f, 0.f, 0.f);
        float4 r;
        r.x = nearest_code(v.x, code);
        r.y = nearest_code(v.y, code);
        r.z = nearest_code(v.z, code);
        r.w = nearest_code(v.w, code);
        if (ok) o4[i] = r;
    }

    // Scalar tail (n % 4 != 0) — same wave-uniform structure.
    const long long tail_start = n4 << 2;
    for (long long b = tail_start + wave_off; b < n; b += stride) {
        const long long i = b + lane;
        const bool ok = i < n;
        float xv = ok ? x[i] : 0.f;
        float r = nearest_code(xv, code);
        if (ok) out[i] = r;
    }
}

extern "C" void kernel_launch(void* const* d_in, const int* in_sizes, int n_in,
                              void* d_out, int out_size, void* d_ws, size_t ws_size,
                              hipStream_t stream) {
    const float* x = (const float*)d_in[0];
    const float* vals = (const float*)d_in[1];
    float* out = (float*)d_out;
    const long long n = (long long)in_sizes[0];

    long long n4 = n >> 2;
    long long want = (n4 + BLOCK - 1) / BLOCK;
    if (want < 1) want = 1;
    int blocks = (int)(want < GRID_CAP ? want : GRID_CAP);

    fp6_nearest_kernel<<<blocks, BLOCK, 0, stream>>>(x, vals, out, n);
}